// Round 1
// baseline (3285.842 us; speedup 1.0000x reference)
//
#include <hip/hip_runtime.h>
#include <hip/hip_bf16.h>
#include <math.h>

// ---------------------------------------------------------------------------
// CoSADUV_NoTemporal: 4x BiLSTM row/col scans + 1x1 conv + sigmoid + bilinear
// Round 1: correct fp32 baseline.
//   N=8, H=60, W=80, HS=128, C=2*HS=256, P=38400 positions.
//   Layer k: gx = x @ Wih^T + b  (GEMM, [38400,K]x[1024,K]^T)
//            recurrence: gates = gx[t] + h @ Whh^T; LSTM cell (i,f,g,o order)
// ---------------------------------------------------------------------------

#define NIMG 8
#define HH_ 60
#define WW_ 80
#define HS_ 128
#define PTOT 38400

__device__ __forceinline__ float rcp_(float x) { return __builtin_amdgcn_rcpf(x); }
__device__ __forceinline__ float fsig(float x) { return rcp_(1.f + __expf(-x)); }
__device__ __forceinline__ float ftanh_(float x) {
  float e = __expf(-2.f * x);
  return 2.f * rcp_(1.f + e) - 1.f;
}

// ---- small FC: sc1[n,512], scr[n,256] from scene_ctx[n,128] ----------------
__global__ void k_fc(const float* __restrict__ ctx, const float* __restrict__ w1,
                     const float* __restrict__ b1, const float* __restrict__ wr,
                     const float* __restrict__ br, float* __restrict__ sc1,
                     float* __restrict__ scr) {
  int n = blockIdx.x;
  __shared__ float c[128];
  int t = threadIdx.x;  // 768 threads
  if (t < 128) c[t] = ctx[n * 128 + t];
  __syncthreads();
  if (t < 512) {
    float a = b1[t];
    const float* wp = w1 + t * 128;
    for (int k = 0; k < 128; k++) a += wp[k] * c[k];
    sc1[n * 512 + t] = a;
  } else {
    int j = t - 512;
    float a = br[j];
    const float* wp = wr + j * 128;
    for (int k = 0; k < 128; k++) a += wp[k] * c[k];
    scr[n * 256 + j] = a;
  }
}

// ---- transpose Whh [2,512,128] -> whhT [2,128,512] -------------------------
__global__ void k_whht(const float* __restrict__ whh, float* __restrict__ wt) {
  __shared__ float tile[32][33];
  int d = blockIdx.z;
  int r0 = blockIdx.x * 32;  // gate row 0..511
  int k0 = blockIdx.y * 32;  // k 0..127
  const float* src = whh + d * 512 * 128;
  float* dst = wt + d * 128 * 512;
  for (int i = threadIdx.y; i < 32; i += 8)
    tile[i][threadIdx.x] = src[(r0 + i) * 128 + k0 + threadIdx.x];
  __syncthreads();
  for (int i = threadIdx.y; i < 32; i += 8)
    dst[(k0 + i) * 512 + r0 + threadIdx.x] = tile[threadIdx.x][i];
}

// ---- prep layer 1: local_feats [8,512,60,80] -> x [8,60,80,512] + sc1 edges
__global__ void k_prep1(const float* __restrict__ lf, const float* __restrict__ sc1,
                        float* __restrict__ x) {
  __shared__ float tile[32][33];
  int n = blockIdx.z;
  int p0 = blockIdx.x * 32;  // position in 4800
  int i0 = blockIdx.y * 32;  // channel
  const float* src = lf + (size_t)n * 512 * 4800;
  for (int r = threadIdx.y; r < 32; r += 8)
    tile[r][threadIdx.x] = src[(size_t)(i0 + r) * 4800 + p0 + threadIdx.x];
  __syncthreads();
  for (int r = threadIdx.y; r < 32; r += 8) {
    int p = p0 + r;
    int w = p % 80;
    int ch = i0 + threadIdx.x;
    float v = tile[threadIdx.x][r];
    if (w == 0 || w == 79) v += sc1[n * 512 + ch];
    x[((size_t)n * 4800 + p) * 512 + ch] = v;
  }
}

// ---- swap prep (layers 2..4): y [n,A,B,256] -> x [n,B,A,256] (+scr at a edges)
__global__ void k_swap(const float* __restrict__ y, const float* __restrict__ sc,
                       float* __restrict__ x, int A, int B) {
  int b = blockIdx.x, a = blockIdx.y, n = blockIdx.z, c = threadIdx.x;
  float v = y[(((size_t)n * A + a) * B + b) * 256 + c];
  if (a == 0 || a == A - 1) v += sc[n * 256 + c];
  x[(((size_t)n * B + b) * A + a) * 256 + c] = v;
}

// ---- fp32 GEMM: C[M,1024] = A[M,K] * W[1024,K]^T + bias  (BM=BN=128, BK=16)
__global__ __launch_bounds__(256) void k_gemm(const float* __restrict__ A,
                                              const float* __restrict__ Wf,
                                              const float* __restrict__ bias,
                                              float* __restrict__ C, int M, int K) {
  __shared__ float As[16][132];
  __shared__ float Bs[16][132];
  int bm = blockIdx.x * 128;
  int bn = blockIdx.y * 128;
  int tid = threadIdx.x;
  int tx = tid & 15, ty = tid >> 4;
  float acc[8][8] = {};
  int lrow = tid >> 1;        // 0..127
  int lk = (tid & 1) * 8;     // 0 or 8
  const float* Ap = A + (size_t)(bm + lrow) * K + lk;
  const float* Bp = Wf + (size_t)(bn + lrow) * K + lk;
  for (int k0 = 0; k0 < K; k0 += 16) {
    float4 a0 = *(const float4*)(Ap + k0);
    float4 a1 = *(const float4*)(Ap + k0 + 4);
    float4 b0 = *(const float4*)(Bp + k0);
    float4 b1 = *(const float4*)(Bp + k0 + 4);
    As[lk + 0][lrow] = a0.x; As[lk + 1][lrow] = a0.y;
    As[lk + 2][lrow] = a0.z; As[lk + 3][lrow] = a0.w;
    As[lk + 4][lrow] = a1.x; As[lk + 5][lrow] = a1.y;
    As[lk + 6][lrow] = a1.z; As[lk + 7][lrow] = a1.w;
    Bs[lk + 0][lrow] = b0.x; Bs[lk + 1][lrow] = b0.y;
    Bs[lk + 2][lrow] = b0.z; Bs[lk + 3][lrow] = b0.w;
    Bs[lk + 4][lrow] = b1.x; Bs[lk + 5][lrow] = b1.y;
    Bs[lk + 6][lrow] = b1.z; Bs[lk + 7][lrow] = b1.w;
    __syncthreads();
#pragma unroll
    for (int k = 0; k < 16; k++) {
      float a_[8], b_[8];
      *(float4*)&a_[0] = *(const float4*)&As[k][ty * 8];
      *(float4*)&a_[4] = *(const float4*)&As[k][ty * 8 + 4];
      *(float4*)&b_[0] = *(const float4*)&Bs[k][tx * 8];
      *(float4*)&b_[4] = *(const float4*)&Bs[k][tx * 8 + 4];
#pragma unroll
      for (int i = 0; i < 8; i++)
#pragma unroll
        for (int j = 0; j < 8; j++) acc[i][j] += a_[i] * b_[j];
    }
    __syncthreads();
  }
#pragma unroll
  for (int i = 0; i < 8; i++) {
    size_t row = (size_t)(bm + ty * 8 + i) * 1024 + bn + tx * 8;
#pragma unroll
    for (int j = 0; j < 8; j++) C[row + j] = acc[i][j] + bias[bn + tx * 8 + j];
  }
}

// ---- BiLSTM recurrence (one direction per block, 4 sequences) --------------
// gx: [Bq, T, 1024] (dir0 gates 0..511, dir1 512..1023), whhT: [2][128][512]
// y:  [Bq, T, 256]  (dir0 -> ch 0..127, dir1 -> 128..255)
__global__ __launch_bounds__(512) void k_lstm(const float* __restrict__ gx,
                                              const float* __restrict__ wt2,
                                              float* __restrict__ y, int Bq, int T) {
  int dir = blockIdx.y;
  int s0 = blockIdx.x * 4;
  const float* wt = wt2 + dir * 128 * 512;
  __shared__ float hsh[4][128];
  __shared__ float gb[4][512];
  int tid = threadIdx.x;  // 0..511 = gate column g
  hsh[tid >> 7][tid & 127] = 0.f;
  float cst = 0.f;
  int s_ = tid >> 7, u_ = tid & 127;
  __syncthreads();
  for (int st = 0; st < T; ++st) {
    int t = dir ? (T - 1 - st) : st;
    size_t base = ((size_t)s0 * T + t) * 1024 + dir * 512 + tid;
    size_t sstride = (size_t)T * 1024;
    float a0 = gx[base];
    float a1 = gx[base + sstride];
    float a2 = gx[base + 2 * sstride];
    float a3 = gx[base + 3 * sstride];
#pragma unroll 8
    for (int k = 0; k < 128; k += 4) {
      float4 h0 = *(const float4*)&hsh[0][k];
      float4 h1 = *(const float4*)&hsh[1][k];
      float4 h2 = *(const float4*)&hsh[2][k];
      float4 h3 = *(const float4*)&hsh[3][k];
      float w0 = wt[(k + 0) * 512 + tid];
      float w1 = wt[(k + 1) * 512 + tid];
      float w2 = wt[(k + 2) * 512 + tid];
      float w3 = wt[(k + 3) * 512 + tid];
      a0 += h0.x * w0 + h0.y * w1 + h0.z * w2 + h0.w * w3;
      a1 += h1.x * w0 + h1.y * w1 + h1.z * w2 + h1.w * w3;
      a2 += h2.x * w0 + h2.y * w1 + h2.z * w2 + h2.w * w3;
      a3 += h3.x * w0 + h3.y * w1 + h3.z * w2 + h3.w * w3;
    }
    gb[0][tid] = a0; gb[1][tid] = a1; gb[2][tid] = a2; gb[3][tid] = a3;
    __syncthreads();
    float i_ = fsig(gb[s_][u_]);
    float f_ = fsig(gb[s_][128 + u_]);
    float g_ = ftanh_(gb[s_][256 + u_]);
    float o_ = fsig(gb[s_][384 + u_]);
    cst = f_ * cst + i_ * g_;
    float h = o_ * ftanh_(cst);
    hsh[s_][u_] = h;
    y[(((size_t)(s0 + s_)) * T + t) * 256 + dir * 128 + u_] = h;
    __syncthreads();
  }
}

// ---- head: 1x1 conv + sigmoid. y4 in [n, w, h, 256] layout -----------------
__global__ void k_head(const float* __restrict__ y, const float* __restrict__ cw,
                       const float* __restrict__ cb, float* __restrict__ score) {
  int wv = threadIdx.x >> 6, ln = threadIdx.x & 63;
  int o = blockIdx.x * 4 + wv;  // o = (n*80 + w)*60 + h
  const float* yp = y + (size_t)o * 256;
  float a = 0.f;
  for (int c = ln; c < 256; c += 64) a += yp[c] * cw[c];
  for (int off = 32; off; off >>= 1) a += __shfl_down(a, off);
  if (ln == 0) {
    int h = o % 60;
    int nw = o / 60;
    int w = nw % 80;
    int n = nw / 80;
    score[(n * 60 + h) * 80 + w] = fsig(a + cb[0]);
  }
}

// ---- bilinear upsample (align_corners=True) 60x80 -> 480x640 ---------------
__global__ void k_up(const float* __restrict__ score, float* __restrict__ out) {
  int idx = blockIdx.x * 256 + threadIdx.x;
  if (idx >= NIMG * 480 * 640) return;
  int ox = idx % 640;
  int t = idx / 640;
  int oy = t % 480;
  int n = t / 480;
  float sy = oy * (59.f / 479.f);
  float sx = ox * (79.f / 639.f);
  int y0 = min((int)sy, 58);
  int x0 = min((int)sx, 78);
  float ty = sy - (float)y0;
  float tx = sx - (float)x0;
  const float* sp = score + n * 4800;
  float v00 = sp[y0 * 80 + x0], v01 = sp[y0 * 80 + x0 + 1];
  float v10 = sp[(y0 + 1) * 80 + x0], v11 = sp[(y0 + 1) * 80 + x0 + 1];
  float v0 = v00 + (v01 - v00) * tx;
  float v1 = v10 + (v11 - v10) * tx;
  out[idx] = v0 + (v1 - v0) * ty;
}

extern "C" void kernel_launch(void* const* d_in, const int* in_sizes, int n_in,
                              void* d_out, int out_size, void* d_ws, size_t ws_size,
                              hipStream_t stream) {
  const float* lf    = (const float*)d_in[0];
  const float* ctx   = (const float*)d_in[1];
  const float* fc1w  = (const float*)d_in[2];
  const float* fc1b  = (const float*)d_in[3];
  const float* fcrw  = (const float*)d_in[4];
  const float* fcrb  = (const float*)d_in[5];
  const float* wih[4] = {(const float*)d_in[6], (const float*)d_in[9],
                         (const float*)d_in[12], (const float*)d_in[15]};
  const float* whh[4] = {(const float*)d_in[7], (const float*)d_in[10],
                         (const float*)d_in[13], (const float*)d_in[16]};
  const float* bb[4]  = {(const float*)d_in[8], (const float*)d_in[11],
                         (const float*)d_in[14], (const float*)d_in[17]};
  const float* convw = (const float*)d_in[18];
  const float* convb = (const float*)d_in[19];
  float* out = (float*)d_out;

  // workspace layout (floats); total 69,381,632 floats = 277.5 MB
  float* ws    = (float*)d_ws;
  float* sc1   = ws;                    // 4096
  float* scr   = ws + 4096;             // 2048
  float* whhT  = ws + 6144;             // 4 * 131072
  float* xbuf  = ws + 530432;           // 38400*512
  float* gxbuf = ws + 20191232;         // 38400*1024
  float* ybuf  = ws + 59512832;         // 38400*256
  float* score = ws + 69343232;         // 38400

  k_fc<<<NIMG, 768, 0, stream>>>(ctx, fc1w, fc1b, fcrw, fcrb, sc1, scr);
  for (int l = 0; l < 4; l++)
    k_whht<<<dim3(16, 4, 2), dim3(32, 8), 0, stream>>>(whh[l], whhT + l * 131072);
  k_prep1<<<dim3(150, 16, NIMG), dim3(32, 8), 0, stream>>>(lf, sc1, xbuf);

  // layer 1: rows (B=480, T=80, K=512)
  k_gemm<<<dim3(300, 8), 256, 0, stream>>>(xbuf, wih[0], bb[0], gxbuf, PTOT, 512);
  k_lstm<<<dim3(120, 2), 512, 0, stream>>>(gxbuf, whhT + 0 * 131072, ybuf, 480, 80);

  // layer 2: cols (y1 [n,60,80,c] -> x2 [n,80,60,c], edge at h)
  k_swap<<<dim3(80, 60, NIMG), 256, 0, stream>>>(ybuf, scr, xbuf, 60, 80);
  k_gemm<<<dim3(300, 8), 256, 0, stream>>>(xbuf, wih[1], bb[1], gxbuf, PTOT, 256);
  k_lstm<<<dim3(160, 2), 512, 0, stream>>>(gxbuf, whhT + 1 * 131072, ybuf, 640, 60);

  // layer 3: rows (y2 [n,80,60,c] -> x3 [n,60,80,c], edge at w)
  k_swap<<<dim3(60, 80, NIMG), 256, 0, stream>>>(ybuf, scr, xbuf, 80, 60);
  k_gemm<<<dim3(300, 8), 256, 0, stream>>>(xbuf, wih[2], bb[2], gxbuf, PTOT, 256);
  k_lstm<<<dim3(120, 2), 512, 0, stream>>>(gxbuf, whhT + 2 * 131072, ybuf, 480, 80);

  // layer 4: cols (y3 [n,60,80,c] -> x4 [n,80,60,c], edge at h)
  k_swap<<<dim3(80, 60, NIMG), 256, 0, stream>>>(ybuf, scr, xbuf, 60, 80);
  k_gemm<<<dim3(300, 8), 256, 0, stream>>>(xbuf, wih[3], bb[3], gxbuf, PTOT, 256);
  k_lstm<<<dim3(160, 2), 512, 0, stream>>>(gxbuf, whhT + 3 * 131072, ybuf, 640, 60);

  // head + upsample
  k_head<<<PTOT / 4, 256, 0, stream>>>(ybuf, convw, convb, score);
  k_up<<<(NIMG * 480 * 640 + 255) / 256, 256, 0, stream>>>(score, out);
}

// Round 2
// 1873.756 us; speedup vs baseline: 1.7536x; 1.7536x over previous
//
#include <hip/hip_runtime.h>
#include <hip/hip_bf16.h>
#include <math.h>

// ---------------------------------------------------------------------------
// CoSADUV_NoTemporal. Round 2: MFMA-based BiLSTM recurrence.
//   Recurrence per step: gates[16,512] = h_bf16[16,128] @ WhhT + gx (fp32 acc)
//   Block = 16 seqs x 1 dir, 8 waves; wave w owns units 16w..16w+15 for all
//   four gates (tiles w, 8+w, 16+w, 24+w) -> cell update fully in-register.
//   Whh resident in VGPRs as bf16 B-fragments. 1 barrier/step.
// ---------------------------------------------------------------------------

#define NIMG 8
#define PTOT 38400
#define PADH 136  // h row stride in bf16 elems (16B-aligned: 136*2=272=17*16)

typedef __attribute__((ext_vector_type(8))) short short8;
typedef __attribute__((ext_vector_type(4))) float float4v;

__device__ __forceinline__ float rcp_(float x) { return __builtin_amdgcn_rcpf(x); }
__device__ __forceinline__ float fsig(float x) { return rcp_(1.f + __expf(-x)); }
__device__ __forceinline__ float ftanh_(float x) {
  float e = __expf(-2.f * x);
  return 2.f * rcp_(1.f + e) - 1.f;
}
__device__ __forceinline__ short f2bf(float v) {
  unsigned ub = __builtin_bit_cast(unsigned, v);
  unsigned rb = (ub + 0x7fffu + ((ub >> 16) & 1u)) >> 16;
  return (short)rb;
}

// ---- small FC: sc1[n,512], scr[n,256] from scene_ctx[n,128] ----------------
__global__ void k_fc(const float* __restrict__ ctx, const float* __restrict__ w1,
                     const float* __restrict__ b1, const float* __restrict__ wr,
                     const float* __restrict__ br, float* __restrict__ sc1,
                     float* __restrict__ scr) {
  int n = blockIdx.x;
  __shared__ float c[128];
  int t = threadIdx.x;  // 768 threads
  if (t < 128) c[t] = ctx[n * 128 + t];
  __syncthreads();
  if (t < 512) {
    float a = b1[t];
    const float* wp = w1 + t * 128;
    for (int k = 0; k < 128; k++) a += wp[k] * c[k];
    sc1[n * 512 + t] = a;
  } else {
    int j = t - 512;
    float a = br[j];
    const float* wp = wr + j * 128;
    for (int k = 0; k < 128; k++) a += wp[k] * c[k];
    scr[n * 256 + j] = a;
  }
}

// ---- pack Whh [2,512,128] f32 -> bf16 B-fragments --------------------------
// layout: [dir][wave 8][G 4][kt 4][lane 64][j 8]; frag element j =
//   B[k = kt*32 + (lane>>4)*8 + j][n = G*128 + w*16 + (lane&15)] = Whh[n][k]
__global__ void k_bfrag(const float* __restrict__ whh, short* __restrict__ out) {
  int idx = blockIdx.x * 512 + threadIdx.x;  // 0..131071
  int j = idx & 7, lane = (idx >> 3) & 63, kt = (idx >> 9) & 3;
  int G = (idx >> 11) & 3, w = (idx >> 13) & 7, dir = idx >> 16;
  int n = G * 128 + w * 16 + (lane & 15);
  int k = kt * 32 + (lane >> 4) * 8 + j;
  out[idx] = f2bf(whh[(dir * 512 + n) * 128 + k]);
}

// ---- prep layer 1: local_feats [8,512,60,80] -> x [8,60,80,512] + sc1 edges
__global__ void k_prep1(const float* __restrict__ lf, const float* __restrict__ sc1,
                        float* __restrict__ x) {
  __shared__ float tile[32][33];
  int n = blockIdx.z;
  int p0 = blockIdx.x * 32;  // position in 4800
  int i0 = blockIdx.y * 32;  // channel
  const float* src = lf + (size_t)n * 512 * 4800;
  for (int r = threadIdx.y; r < 32; r += 8)
    tile[r][threadIdx.x] = src[(size_t)(i0 + r) * 4800 + p0 + threadIdx.x];
  __syncthreads();
  for (int r = threadIdx.y; r < 32; r += 8) {
    int p = p0 + r;
    int w = p % 80;
    int ch = i0 + threadIdx.x;
    float v = tile[threadIdx.x][r];
    if (w == 0 || w == 79) v += sc1[n * 512 + ch];
    x[((size_t)n * 4800 + p) * 512 + ch] = v;
  }
}

// ---- swap prep (layers 2..4): y [n,A,B,256] -> x [n,B,A,256] (+scr at a edges)
__global__ void k_swap(const float* __restrict__ y, const float* __restrict__ sc,
                       float* __restrict__ x, int A, int B) {
  int b = blockIdx.x, a = blockIdx.y, n = blockIdx.z, c = threadIdx.x;
  float v = y[(((size_t)n * A + a) * B + b) * 256 + c];
  if (a == 0 || a == A - 1) v += sc[n * 256 + c];
  x[(((size_t)n * B + b) * A + a) * 256 + c] = v;
}

// ---- fp32 GEMM: C[M,1024] = A[M,K] * W[1024,K]^T + bias  (BM=BN=128, BK=16)
__global__ __launch_bounds__(256) void k_gemm(const float* __restrict__ A,
                                              const float* __restrict__ Wf,
                                              const float* __restrict__ bias,
                                              float* __restrict__ C, int M, int K) {
  __shared__ float As[16][132];
  __shared__ float Bs[16][132];
  int bm = blockIdx.x * 128;
  int bn = blockIdx.y * 128;
  int tid = threadIdx.x;
  int tx = tid & 15, ty = tid >> 4;
  float acc[8][8] = {};
  int lrow = tid >> 1;
  int lk = (tid & 1) * 8;
  const float* Ap = A + (size_t)(bm + lrow) * K + lk;
  const float* Bp = Wf + (size_t)(bn + lrow) * K + lk;
  for (int k0 = 0; k0 < K; k0 += 16) {
    float4 a0 = *(const float4*)(Ap + k0);
    float4 a1 = *(const float4*)(Ap + k0 + 4);
    float4 b0 = *(const float4*)(Bp + k0);
    float4 b1 = *(const float4*)(Bp + k0 + 4);
    As[lk + 0][lrow] = a0.x; As[lk + 1][lrow] = a0.y;
    As[lk + 2][lrow] = a0.z; As[lk + 3][lrow] = a0.w;
    As[lk + 4][lrow] = a1.x; As[lk + 5][lrow] = a1.y;
    As[lk + 6][lrow] = a1.z; As[lk + 7][lrow] = a1.w;
    Bs[lk + 0][lrow] = b0.x; Bs[lk + 1][lrow] = b0.y;
    Bs[lk + 2][lrow] = b0.z; Bs[lk + 3][lrow] = b0.w;
    Bs[lk + 4][lrow] = b1.x; Bs[lk + 5][lrow] = b1.y;
    Bs[lk + 6][lrow] = b1.z; Bs[lk + 7][lrow] = b1.w;
    __syncthreads();
#pragma unroll
    for (int k = 0; k < 16; k++) {
      float a_[8], b_[8];
      *(float4*)&a_[0] = *(const float4*)&As[k][ty * 8];
      *(float4*)&a_[4] = *(const float4*)&As[k][ty * 8 + 4];
      *(float4*)&b_[0] = *(const float4*)&Bs[k][tx * 8];
      *(float4*)&b_[4] = *(const float4*)&Bs[k][tx * 8 + 4];
#pragma unroll
      for (int i = 0; i < 8; i++)
#pragma unroll
        for (int j = 0; j < 8; j++) acc[i][j] += a_[i] * b_[j];
    }
    __syncthreads();
  }
#pragma unroll
  for (int i = 0; i < 8; i++) {
    size_t row = (size_t)(bm + ty * 8 + i) * 1024 + bn + tx * 8;
#pragma unroll
    for (int j = 0; j < 8; j++) C[row + j] = acc[i][j] + bias[bn + tx * 8 + j];
  }
}

// ---- MFMA BiLSTM recurrence ------------------------------------------------
// gx: [Bq, T, 1024] (dir0 gates 0..511, dir1 512..1023)
// bfr: packed bf16 Whh fragments (see k_bfrag)
// y:  [Bq, T, 256]  (dir0 -> ch 0..127, dir1 -> 128..255)
// grid: (Bq/16, 2); block: 512 = 8 waves
__global__ __launch_bounds__(512, 2) void k_lstm2(const float* __restrict__ gx,
                                                  const short* __restrict__ bfr,
                                                  float* __restrict__ y, int T) {
  int dir = blockIdx.y;
  int s0 = blockIdx.x * 16;
  int tid = threadIdx.x;
  int w = tid >> 6;
  int lane = tid & 63;
  int ln = lane & 15, quad = lane >> 4;
  int u = w * 16 + ln;  // unit 0..127 owned by this lane

  __shared__ __align__(16) short hbuf[2][16 * PADH];

  // load resident B-fragments: bfrag[G][kt]
  short8 bfrag[4][4];
  const short* bp = bfr + ((size_t)dir * 8 + w) * 8192;
#pragma unroll
  for (int G = 0; G < 4; G++)
#pragma unroll
    for (int kt = 0; kt < 4; kt++)
      bfrag[G][kt] = *(const short8*)(bp + ((G * 4 + kt) * 64 + lane) * 8);

  for (int i = tid; i < 16 * PADH; i += 512) hbuf[0][i] = 0;

  float c[4] = {0.f, 0.f, 0.f, 0.f};
  float gc[4][4], gn[4][4];  // gx prefetch regs [G][r]
  const float* gbase = gx + ((size_t)(s0 + quad * 4) * T) * 1024 + dir * 512 + u;
  size_t sstride = (size_t)T * 1024;

  {
    int t0 = dir ? (T - 1) : 0;
#pragma unroll
    for (int r = 0; r < 4; r++)
#pragma unroll
      for (int G = 0; G < 4; G++) gc[G][r] = gbase[r * sstride + (size_t)t0 * 1024 + G * 128];
  }
  __syncthreads();

  for (int st = 0; st < T; ++st) {
    int t = dir ? (T - 1 - st) : st;
    if (st + 1 < T) {
      int tn = dir ? (T - 2 - st) : (st + 1);
#pragma unroll
      for (int r = 0; r < 4; r++)
#pragma unroll
        for (int G = 0; G < 4; G++) gn[G][r] = gbase[r * sstride + (size_t)tn * 1024 + G * 128];
    }
    int pb = st & 1;
    // A-fragments: h_bf16[seq = ln][k = kt*32 + quad*8 + j]
    short8 af[4];
    const short* hp = &hbuf[pb][ln * PADH + quad * 8];
#pragma unroll
    for (int kt = 0; kt < 4; kt++) af[kt] = *(const short8*)(hp + kt * 32);

    float4v acc[4];
#pragma unroll
    for (int G = 0; G < 4; G++) {
      float4v a = {gc[G][0], gc[G][1], gc[G][2], gc[G][3]};
#pragma unroll
      for (int kt = 0; kt < 4; kt++)
        a = __builtin_amdgcn_mfma_f32_16x16x32_bf16(af[kt], bfrag[G][kt], a, 0, 0, 0);
      acc[G] = a;
    }
    // cell update: acc[0]=i, acc[1]=f, acc[2]=g, acc[3]=o; reg r = seq quad*4+r
    float hv[4];
#pragma unroll
    for (int r = 0; r < 4; r++) {
      float iv = fsig(acc[0][r]);
      float fv = fsig(acc[1][r]);
      float gv = ftanh_(acc[2][r]);
      float ov = fsig(acc[3][r]);
      c[r] = fv * c[r] + iv * gv;
      hv[r] = ov * ftanh_(c[r]);
    }
#pragma unroll
    for (int r = 0; r < 4; r++) {
      hbuf[1 - pb][(quad * 4 + r) * PADH + u] = f2bf(hv[r]);
      y[((size_t)(s0 + quad * 4 + r) * T + t) * 256 + dir * 128 + u] = hv[r];
    }
    if (st + 1 < T) {
#pragma unroll
      for (int G = 0; G < 4; G++)
#pragma unroll
        for (int r = 0; r < 4; r++) gc[G][r] = gn[G][r];
    }
    __syncthreads();
  }
}

// ---- head: 1x1 conv + sigmoid. y4 in [n, w, h, 256] layout -----------------
__global__ void k_head(const float* __restrict__ y, const float* __restrict__ cw,
                       const float* __restrict__ cb, float* __restrict__ score) {
  int wv = threadIdx.x >> 6, ln = threadIdx.x & 63;
  int o = blockIdx.x * 4 + wv;  // o = (n*80 + w)*60 + h
  const float* yp = y + (size_t)o * 256;
  float a = 0.f;
  for (int c = ln; c < 256; c += 64) a += yp[c] * cw[c];
  for (int off = 32; off; off >>= 1) a += __shfl_down(a, off);
  if (ln == 0) {
    int h = o % 60;
    int nw = o / 60;
    int w = nw % 80;
    int n = nw / 80;
    score[(n * 60 + h) * 80 + w] = fsig(a + cb[0]);
  }
}

// ---- bilinear upsample (align_corners=True) 60x80 -> 480x640 ---------------
__global__ void k_up(const float* __restrict__ score, float* __restrict__ out) {
  int idx = blockIdx.x * 256 + threadIdx.x;
  if (idx >= NIMG * 480 * 640) return;
  int ox = idx % 640;
  int t = idx / 640;
  int oy = t % 480;
  int n = t / 480;
  float sy = oy * (59.f / 479.f);
  float sx = ox * (79.f / 639.f);
  int y0 = min((int)sy, 58);
  int x0 = min((int)sx, 78);
  float ty = sy - (float)y0;
  float tx = sx - (float)x0;
  const float* sp = score + n * 4800;
  float v00 = sp[y0 * 80 + x0], v01 = sp[y0 * 80 + x0 + 1];
  float v10 = sp[(y0 + 1) * 80 + x0], v11 = sp[(y0 + 1) * 80 + x0 + 1];
  float v0 = v00 + (v01 - v00) * tx;
  float v1 = v10 + (v11 - v10) * tx;
  out[idx] = v0 + (v1 - v0) * ty;
}

extern "C" void kernel_launch(void* const* d_in, const int* in_sizes, int n_in,
                              void* d_out, int out_size, void* d_ws, size_t ws_size,
                              hipStream_t stream) {
  const float* lf    = (const float*)d_in[0];
  const float* ctx   = (const float*)d_in[1];
  const float* fc1w  = (const float*)d_in[2];
  const float* fc1b  = (const float*)d_in[3];
  const float* fcrw  = (const float*)d_in[4];
  const float* fcrb  = (const float*)d_in[5];
  const float* wih[4] = {(const float*)d_in[6], (const float*)d_in[9],
                         (const float*)d_in[12], (const float*)d_in[15]};
  const float* whh[4] = {(const float*)d_in[7], (const float*)d_in[10],
                         (const float*)d_in[13], (const float*)d_in[16]};
  const float* bb[4]  = {(const float*)d_in[8], (const float*)d_in[11],
                         (const float*)d_in[14], (const float*)d_in[17]};
  const float* convw = (const float*)d_in[18];
  const float* convb = (const float*)d_in[19];
  float* out = (float*)d_out;

  float* ws    = (float*)d_ws;
  float* sc1   = ws;                    // 4096
  float* scr   = ws + 4096;             // 2048
  short* bfr   = (short*)(ws + 6144);   // 4 layers * 131072 shorts (262144 f)
  float* xbuf  = ws + 530432;           // 38400*512
  float* gxbuf = ws + 20191232;         // 38400*1024
  float* ybuf  = ws + 59512832;         // 38400*256
  float* score = ws + 69343232;         // 38400

  k_fc<<<NIMG, 768, 0, stream>>>(ctx, fc1w, fc1b, fcrw, fcrb, sc1, scr);
  for (int l = 0; l < 4; l++)
    k_bfrag<<<256, 512, 0, stream>>>(whh[l], bfr + (size_t)l * 131072);
  k_prep1<<<dim3(150, 16, NIMG), dim3(32, 8), 0, stream>>>(lf, sc1, xbuf);

  // layer 1: rows (480 seqs, T=80, K=512)
  k_gemm<<<dim3(300, 8), 256, 0, stream>>>(xbuf, wih[0], bb[0], gxbuf, PTOT, 512);
  k_lstm2<<<dim3(30, 2), 512, 0, stream>>>(gxbuf, bfr + 0 * 131072, ybuf, 80);

  // layer 2: cols (640 seqs, T=60)
  k_swap<<<dim3(80, 60, NIMG), 256, 0, stream>>>(ybuf, scr, xbuf, 60, 80);
  k_gemm<<<dim3(300, 8), 256, 0, stream>>>(xbuf, wih[1], bb[1], gxbuf, PTOT, 256);
  k_lstm2<<<dim3(40, 2), 512, 0, stream>>>(gxbuf, bfr + 1 * 131072, ybuf, 60);

  // layer 3: rows (480 seqs, T=80)
  k_swap<<<dim3(60, 80, NIMG), 256, 0, stream>>>(ybuf, scr, xbuf, 80, 60);
  k_gemm<<<dim3(300, 8), 256, 0, stream>>>(xbuf, wih[2], bb[2], gxbuf, PTOT, 256);
  k_lstm2<<<dim3(30, 2), 512, 0, stream>>>(gxbuf, bfr + 2 * 131072, ybuf, 80);

  // layer 4: cols (640 seqs, T=60)
  k_swap<<<dim3(80, 60, NIMG), 256, 0, stream>>>(ybuf, scr, xbuf, 60, 80);
  k_gemm<<<dim3(300, 8), 256, 0, stream>>>(xbuf, wih[3], bb[3], gxbuf, PTOT, 256);
  k_lstm2<<<dim3(40, 2), 512, 0, stream>>>(gxbuf, bfr + 3 * 131072, ybuf, 60);

  // head + upsample
  k_head<<<PTOT / 4, 256, 0, stream>>>(ybuf, convw, convb, score);
  k_up<<<(NIMG * 480 * 640 + 255) / 256, 256, 0, stream>>>(score, out);
}

// Round 3
// 866.531 us; speedup vs baseline: 3.7920x; 2.1624x over previous
//
#include <hip/hip_runtime.h>
#include <hip/hip_bf16.h>
#include <math.h>

// ---------------------------------------------------------------------------
// CoSADUV_NoTemporal. Round 3: full fp16 MFMA pipeline.
//   - gx GEMM: mfma_f32_16x16x32_f16, 128x128 tile, BK=32, global_load_lds.
//   - recurrence: fp16 MFMA (round-2 structure, fp16 frags).
//   - x, gx, y buffers fp16; cell state + activations fp32.
// ---------------------------------------------------------------------------

#define NIMG 8
#define PTOT 38400
#define PADH 136  // h row stride in fp16 elems (16B aligned: 136*2=272)

typedef _Float16 half8 __attribute__((ext_vector_type(8)));
typedef float float4v __attribute__((ext_vector_type(4)));
typedef __attribute__((address_space(1))) const void gvoid_t;
typedef __attribute__((address_space(3))) void svoid_t;

__device__ __forceinline__ void gload16(void* s, const void* g) {
  __builtin_amdgcn_global_load_lds((gvoid_t*)g, (svoid_t*)s, 16, 0, 0);
}

__device__ __forceinline__ float rcp_(float x) { return __builtin_amdgcn_rcpf(x); }
__device__ __forceinline__ float fsig(float x) { return rcp_(1.f + __expf(-x)); }
__device__ __forceinline__ float ftanh_(float x) {
  float e = __expf(-2.f * x);
  return 2.f * rcp_(1.f + e) - 1.f;
}

// ---- small FC: sc1[n,512], scr[n,256] from scene_ctx[n,128] ----------------
__global__ void k_fc(const float* __restrict__ ctx, const float* __restrict__ w1,
                     const float* __restrict__ b1, const float* __restrict__ wr,
                     const float* __restrict__ br, float* __restrict__ sc1,
                     float* __restrict__ scr) {
  int n = blockIdx.x;
  __shared__ float c[128];
  int t = threadIdx.x;  // 768 threads
  if (t < 128) c[t] = ctx[n * 128 + t];
  __syncthreads();
  if (t < 512) {
    float a = b1[t];
    const float* wp = w1 + t * 128;
    for (int k = 0; k < 128; k++) a += wp[k] * c[k];
    sc1[n * 512 + t] = a;
  } else {
    int j = t - 512;
    float a = br[j];
    const float* wp = wr + j * 128;
    for (int k = 0; k < 128; k++) a += wp[k] * c[k];
    scr[n * 256 + j] = a;
  }
}

// ---- pack Whh [2,512,128] f32 -> fp16 B-fragments --------------------------
// layout: [dir][wave 8][G 4][kt 4][lane 64][j 8]; frag element j =
//   B[k = kt*32 + (lane>>4)*8 + j][n = G*128 + w*16 + (lane&15)] = Whh[n][k]
__global__ void k_hfrag(const float* __restrict__ whh, _Float16* __restrict__ out) {
  int idx = blockIdx.x * 512 + threadIdx.x;  // 0..131071
  int j = idx & 7, lane = (idx >> 3) & 63, kt = (idx >> 9) & 3;
  int G = (idx >> 11) & 3, w = (idx >> 13) & 7, dir = idx >> 16;
  int n = G * 128 + w * 16 + (lane & 15);
  int k = kt * 32 + (lane >> 4) * 8 + j;
  out[idx] = (_Float16)whh[(dir * 512 + n) * 128 + k];
}

// ---- pack Wih f32 [1024,K] -> fp16 -----------------------------------------
__global__ void k_wpack(const float* __restrict__ in, _Float16* __restrict__ out, int n) {
  int i = blockIdx.x * 512 + threadIdx.x;
  if (i < n) out[i] = (_Float16)in[i];
}

// ---- prep layer 1: local_feats [8,512,60,80] -> x fp16 [8,60,80,512] -------
__global__ void k_prep1(const float* __restrict__ lf, const float* __restrict__ sc1,
                        _Float16* __restrict__ x) {
  __shared__ float tile[32][33];
  int n = blockIdx.z;
  int p0 = blockIdx.x * 32;  // position in 4800
  int i0 = blockIdx.y * 32;  // channel
  const float* src = lf + (size_t)n * 512 * 4800;
  for (int r = threadIdx.y; r < 32; r += 8)
    tile[r][threadIdx.x] = src[(size_t)(i0 + r) * 4800 + p0 + threadIdx.x];
  __syncthreads();
  for (int r = threadIdx.y; r < 32; r += 8) {
    int p = p0 + r;
    int w = p % 80;
    int ch = i0 + threadIdx.x;
    float v = tile[threadIdx.x][r];
    if (w == 0 || w == 79) v += sc1[n * 512 + ch];
    x[((size_t)n * 4800 + p) * 512 + ch] = (_Float16)v;
  }
}

// ---- swap prep: y fp16 [n,A,B,256] -> x fp16 [n,B,A,256] (+scr at a edges) -
__global__ void k_swap(const _Float16* __restrict__ y, const float* __restrict__ sc,
                       _Float16* __restrict__ x, int A, int B) {
  int b = blockIdx.x, a = blockIdx.y, n = blockIdx.z, c = threadIdx.x;
  float v = (float)y[(((size_t)n * A + a) * B + b) * 256 + c];
  if (a == 0 || a == A - 1) v += sc[n * 256 + c];
  x[(((size_t)n * B + b) * A + a) * 256 + c] = (_Float16)v;
}

// ---- fp16 MFMA GEMM: C[M,1024] = A[M,K] * W[1024,K]^T + bias ---------------
// grid (M/128, 8), block 256 = 4 waves (2x2 of 64x64), BK=32.
__global__ __launch_bounds__(256) void k_gemm_h(const _Float16* __restrict__ A,
                                                const _Float16* __restrict__ W,
                                                const float* __restrict__ bias,
                                                _Float16* __restrict__ C, int K) {
  __shared__ _Float16 As[128 * 32];
  __shared__ _Float16 Bs[128 * 32];
  int bm = blockIdx.x * 128, bn = blockIdx.y * 128;
  int tid = threadIdx.x;
  int w = tid >> 6, lane = tid & 63;
  int ln = lane & 15, quad = lane >> 4;
  int Wm = (w >> 1) * 64, Wn = (w & 1) * 64;
  int srow = w * 16 + (lane >> 2);   // staging row within a 64-row half
  int scol = (lane & 3) * 8;         // k-offset (8 halves = 16 B)
  const _Float16* Ap0 = A + (size_t)(bm + srow) * K + scol;
  const _Float16* Ap1 = A + (size_t)(bm + 64 + srow) * K + scol;
  const _Float16* Bp0 = W + (size_t)(bn + srow) * K + scol;
  const _Float16* Bp1 = W + (size_t)(bn + 64 + srow) * K + scol;
  _Float16* sA0 = As + (w * 16) * 32;
  _Float16* sA1 = As + (64 + w * 16) * 32;
  _Float16* sB0 = Bs + (w * 16) * 32;
  _Float16* sB1 = Bs + (64 + w * 16) * 32;

  float4v acc[4][4];
#pragma unroll
  for (int i = 0; i < 4; i++)
#pragma unroll
    for (int j = 0; j < 4; j++) acc[i][j] = (float4v){0.f, 0.f, 0.f, 0.f};

  for (int k0 = 0; k0 < K; k0 += 32) {
    gload16(sA0, Ap0 + k0);
    gload16(sA1, Ap1 + k0);
    gload16(sB0, Bp0 + k0);
    gload16(sB1, Bp1 + k0);
    __syncthreads();
    const _Float16* ar = As + (Wm + ln) * 32 + quad * 8;
    const _Float16* br = Bs + (Wn + ln) * 32 + quad * 8;
    half8 af[4], bf_[4];
#pragma unroll
    for (int mt = 0; mt < 4; mt++) af[mt] = *(const half8*)(ar + mt * 512);
#pragma unroll
    for (int nt = 0; nt < 4; nt++) bf_[nt] = *(const half8*)(br + nt * 512);
#pragma unroll
    for (int mt = 0; mt < 4; mt++)
#pragma unroll
      for (int nt = 0; nt < 4; nt++)
        acc[mt][nt] = __builtin_amdgcn_mfma_f32_16x16x32_f16(af[mt], bf_[nt],
                                                             acc[mt][nt], 0, 0, 0);
    __syncthreads();
  }
#pragma unroll
  for (int nt = 0; nt < 4; nt++) {
    int col = bn + Wn + nt * 16 + ln;
    float bv = bias[col];
#pragma unroll
    for (int mt = 0; mt < 4; mt++) {
      size_t rbase = (size_t)(bm + Wm + mt * 16 + quad * 4) * 1024 + col;
#pragma unroll
      for (int r = 0; r < 4; r++)
        C[rbase + (size_t)r * 1024] = (_Float16)(acc[mt][nt][r] + bv);
    }
  }
}

// ---- fp16 MFMA BiLSTM recurrence -------------------------------------------
// gx: fp16 [Bq, T, 1024]; bfr: packed fp16 Whh frags; y: fp16 [Bq, T, 256]
// grid: (Bq/16, 2); block: 512 = 8 waves
__global__ __launch_bounds__(512, 2) void k_lstm2(const _Float16* __restrict__ gx,
                                                  const _Float16* __restrict__ bfr,
                                                  _Float16* __restrict__ y, int T) {
  int dir = blockIdx.y;
  int s0 = blockIdx.x * 16;
  int tid = threadIdx.x;
  int w = tid >> 6;
  int lane = tid & 63;
  int ln = lane & 15, quad = lane >> 4;
  int u = w * 16 + ln;  // unit 0..127 owned by this lane

  __shared__ __align__(16) _Float16 hbuf[2][16 * PADH];

  // resident B-fragments: bfrag[G][kt]
  half8 bfrag[4][4];
  const _Float16* bp = bfr + ((size_t)dir * 8 + w) * 8192;
#pragma unroll
  for (int G = 0; G < 4; G++)
#pragma unroll
    for (int kt = 0; kt < 4; kt++)
      bfrag[G][kt] = *(const half8*)(bp + ((G * 4 + kt) * 64 + lane) * 8);

  for (int i = tid; i < 16 * PADH; i += 512) hbuf[0][i] = (_Float16)0.f;

  float c[4] = {0.f, 0.f, 0.f, 0.f};
  float gc[4][4], gn[4][4];  // gx prefetch regs [G][r]
  const _Float16* gbase = gx + ((size_t)(s0 + quad * 4) * T) * 1024 + dir * 512 + u;
  size_t sstride = (size_t)T * 1024;

  {
    int t0 = dir ? (T - 1) : 0;
#pragma unroll
    for (int r = 0; r < 4; r++)
#pragma unroll
      for (int G = 0; G < 4; G++)
        gc[G][r] = (float)gbase[r * sstride + (size_t)t0 * 1024 + G * 128];
  }
  __syncthreads();

  for (int st = 0; st < T; ++st) {
    int t = dir ? (T - 1 - st) : st;
    if (st + 1 < T) {
      int tn = dir ? (T - 2 - st) : (st + 1);
#pragma unroll
      for (int r = 0; r < 4; r++)
#pragma unroll
        for (int G = 0; G < 4; G++)
          gn[G][r] = (float)gbase[r * sstride + (size_t)tn * 1024 + G * 128];
    }
    int pb = st & 1;
    // A-fragments: h_fp16[seq = ln][k = kt*32 + quad*8 + j]
    half8 af[4];
    const _Float16* hp = &hbuf[pb][ln * PADH + quad * 8];
#pragma unroll
    for (int kt = 0; kt < 4; kt++) af[kt] = *(const half8*)(hp + kt * 32);

    float4v acc[4];
#pragma unroll
    for (int G = 0; G < 4; G++) {
      float4v a = {gc[G][0], gc[G][1], gc[G][2], gc[G][3]};
#pragma unroll
      for (int kt = 0; kt < 4; kt++)
        a = __builtin_amdgcn_mfma_f32_16x16x32_f16(af[kt], bfrag[G][kt], a, 0, 0, 0);
      acc[G] = a;
    }
    // cell update: acc[0]=i, acc[1]=f, acc[2]=g, acc[3]=o; reg r = seq quad*4+r
    float hv[4];
#pragma unroll
    for (int r = 0; r < 4; r++) {
      float iv = fsig(acc[0][r]);
      float fv = fsig(acc[1][r]);
      float gv = ftanh_(acc[2][r]);
      float ov = fsig(acc[3][r]);
      c[r] = fv * c[r] + iv * gv;
      hv[r] = ov * ftanh_(c[r]);
    }
#pragma unroll
    for (int r = 0; r < 4; r++) {
      hbuf[1 - pb][(quad * 4 + r) * PADH + u] = (_Float16)hv[r];
      y[((size_t)(s0 + quad * 4 + r) * T + t) * 256 + dir * 128 + u] = (_Float16)hv[r];
    }
    if (st + 1 < T) {
#pragma unroll
      for (int G = 0; G < 4; G++)
#pragma unroll
        for (int r = 0; r < 4; r++) gc[G][r] = gn[G][r];
    }
    __syncthreads();
  }
}

// ---- head: 1x1 conv + sigmoid. y4 in [n, w, h, 256] fp16 layout ------------
__global__ void k_head(const _Float16* __restrict__ y, const float* __restrict__ cw,
                       const float* __restrict__ cb, float* __restrict__ score) {
  int wv = threadIdx.x >> 6, ln = threadIdx.x & 63;
  int o = blockIdx.x * 4 + wv;  // o = (n*80 + w)*60 + h
  const _Float16* yp = y + (size_t)o * 256;
  float a = 0.f;
  for (int c = ln; c < 256; c += 64) a += (float)yp[c] * cw[c];
  for (int off = 32; off; off >>= 1) a += __shfl_down(a, off);
  if (ln == 0) {
    int h = o % 60;
    int nw = o / 60;
    int w = nw % 80;
    int n = nw / 80;
    score[(n * 60 + h) * 80 + w] = fsig(a + cb[0]);
  }
}

// ---- bilinear upsample (align_corners=True) 60x80 -> 480x640 ---------------
__global__ void k_up(const float* __restrict__ score, float* __restrict__ out) {
  int idx = blockIdx.x * 256 + threadIdx.x;
  if (idx >= NIMG * 480 * 640) return;
  int ox = idx % 640;
  int t = idx / 640;
  int oy = t % 480;
  int n = t / 480;
  float sy = oy * (59.f / 479.f);
  float sx = ox * (79.f / 639.f);
  int y0 = min((int)sy, 58);
  int x0 = min((int)sx, 78);
  float ty = sy - (float)y0;
  float tx = sx - (float)x0;
  const float* sp = score + n * 4800;
  float v00 = sp[y0 * 80 + x0], v01 = sp[y0 * 80 + x0 + 1];
  float v10 = sp[(y0 + 1) * 80 + x0], v11 = sp[(y0 + 1) * 80 + x0 + 1];
  float v0 = v00 + (v01 - v00) * tx;
  float v1 = v10 + (v11 - v10) * tx;
  out[idx] = v0 + (v1 - v0) * ty;
}

extern "C" void kernel_launch(void* const* d_in, const int* in_sizes, int n_in,
                              void* d_out, int out_size, void* d_ws, size_t ws_size,
                              hipStream_t stream) {
  const float* lf    = (const float*)d_in[0];
  const float* ctx   = (const float*)d_in[1];
  const float* fc1w  = (const float*)d_in[2];
  const float* fc1b  = (const float*)d_in[3];
  const float* fcrw  = (const float*)d_in[4];
  const float* fcrb  = (const float*)d_in[5];
  const float* wih[4] = {(const float*)d_in[6], (const float*)d_in[9],
                         (const float*)d_in[12], (const float*)d_in[15]};
  const float* whh[4] = {(const float*)d_in[7], (const float*)d_in[10],
                         (const float*)d_in[13], (const float*)d_in[16]};
  const float* bb[4]  = {(const float*)d_in[8], (const float*)d_in[11],
                         (const float*)d_in[14], (const float*)d_in[17]};
  const float* convw = (const float*)d_in[18];
  const float* convb = (const float*)d_in[19];
  float* out = (float*)d_out;

  // workspace: floats first, then fp16 region (16B-aligned offsets)
  float* ws    = (float*)d_ws;
  float* sc1   = ws;            // 4096
  float* scr   = ws + 4096;     // 2048
  float* score = ws + 6144;     // 38400
  _Float16* hb = (_Float16*)(ws + 44544);
  _Float16* hfr  = hb;                 // 4 * 131072
  _Float16* wpk  = hb + 524288;        // 524288 + 3*262144 = 1310720
  _Float16* xbuf = hb + 1835008;       // 38400*512
  _Float16* gxh  = hb + 21495808;      // 38400*1024
  _Float16* ybuf = hb + 60817408;      // 38400*256
  _Float16* wpkL[4] = {wpk, wpk + 524288, wpk + 786432, wpk + 1048576};

  k_fc<<<NIMG, 768, 0, stream>>>(ctx, fc1w, fc1b, fcrw, fcrb, sc1, scr);
  for (int l = 0; l < 4; l++)
    k_hfrag<<<256, 512, 0, stream>>>(whh[l], hfr + (size_t)l * 131072);
  k_wpack<<<1024, 512, 0, stream>>>(wih[0], wpkL[0], 524288);
  for (int l = 1; l < 4; l++)
    k_wpack<<<512, 512, 0, stream>>>(wih[l], wpkL[l], 262144);
  k_prep1<<<dim3(150, 16, NIMG), dim3(32, 8), 0, stream>>>(lf, sc1, xbuf);

  // layer 1: rows (480 seqs, T=80, K=512)
  k_gemm_h<<<dim3(300, 8), 256, 0, stream>>>(xbuf, wpkL[0], bb[0], gxh, 512);
  k_lstm2<<<dim3(30, 2), 512, 0, stream>>>(gxh, hfr + 0 * 131072, ybuf, 80);

  // layer 2: cols (640 seqs, T=60)
  k_swap<<<dim3(80, 60, NIMG), 256, 0, stream>>>(ybuf, scr, xbuf, 60, 80);
  k_gemm_h<<<dim3(300, 8), 256, 0, stream>>>(xbuf, wpkL[1], bb[1], gxh, 256);
  k_lstm2<<<dim3(40, 2), 512, 0, stream>>>(gxh, hfr + 1 * 131072, ybuf, 60);

  // layer 3: rows (480 seqs, T=80)
  k_swap<<<dim3(60, 80, NIMG), 256, 0, stream>>>(ybuf, scr, xbuf, 80, 60);
  k_gemm_h<<<dim3(300, 8), 256, 0, stream>>>(xbuf, wpkL[2], bb[2], gxh, 256);
  k_lstm2<<<dim3(30, 2), 512, 0, stream>>>(gxh, hfr + 2 * 131072, ybuf, 80);

  // layer 4: cols (640 seqs, T=60)
  k_swap<<<dim3(80, 60, NIMG), 256, 0, stream>>>(ybuf, scr, xbuf, 60, 80);
  k_gemm_h<<<dim3(300, 8), 256, 0, stream>>>(xbuf, wpkL[3], bb[3], gxh, 256);
  k_lstm2<<<dim3(40, 2), 512, 0, stream>>>(gxh, hfr + 3 * 131072, ybuf, 60);

  // head + upsample
  k_head<<<PTOT / 4, 256, 0, stream>>>(ybuf, convw, convb, score);
  k_up<<<(NIMG * 480 * 640 + 255) / 256, 256, 0, stream>>>(score, out);
}